// Round 6
// baseline (198.571 us; speedup 1.0000x reference)
//
#include <hip/hip_runtime.h>
#include <stdint.h>
#include <stddef.h>

// Problem constants (fixed by setup_inputs)
#define NB   2      // batch
#define NL   2048   // seq len
#define ND   512    // model dim
#define NH   8      // heads
#define DH   64     // dim head
#define LOG2E 1.44269504f
#define RG_TOT 32768  // NB*NH*NL rows of partials
#define JS   4      // split-j factor

typedef __attribute__((ext_vector_type(8))) short bf16x8;
typedef __attribute__((ext_vector_type(4))) float f32x4;

__device__ __forceinline__ unsigned short f2bf(float f) {
  union { float f; unsigned int u; } c; c.f = f;
  unsigned int u = c.u;
  unsigned int r = u + 0x7fffu + ((u >> 16) & 1u);
  return (unsigned short)(r >> 16);
}

__device__ __forceinline__ float fexp2(float x) {
#if __has_builtin(__builtin_amdgcn_exp2f)
  return __builtin_amdgcn_exp2f(x);
#else
  return exp2f(x);
#endif
}

// async global->LDS 16B copy; lanes of a wave must target base + lane*16
__device__ __forceinline__ void gl_lds16(const unsigned short* g, unsigned short* l) {
#if __has_builtin(__builtin_amdgcn_global_load_lds)
  __builtin_amdgcn_global_load_lds(
      (const __attribute__((address_space(1))) unsigned int*)g,
      (__attribute__((address_space(3))) unsigned int*)l, 16, 0, 0);
#else
  *(uint4*)l = *(const uint4*)g;
#endif
}

// ---------------------------------------------------------------------------
// f32 -> bf16 conversion for x, w_qkv, w_out + zero-padded positions buffer
// ---------------------------------------------------------------------------
#define XC  524288   // 4096*512/4
#define WQC 196608   // 1536*512/4
#define WOC 65536    // 512*512/4
#define TOTC (XC + WQC + WOC)
__global__ void cvt_f32_bf16(const float* __restrict__ x, const float* __restrict__ wq,
                             const float* __restrict__ wo, const float* __restrict__ positions,
                             const int* __restrict__ ns_p,
                             unsigned short* __restrict__ xb, unsigned short* __restrict__ wqb,
                             unsigned short* __restrict__ wob, float* __restrict__ pospad) {
  int idx = blockIdx.x * 256 + threadIdx.x;
  if (idx < TOTC) {
    const float* src; unsigned short* dst; int off;
    if (idx < XC)            { src = x;  dst = xb;  off = idx; }
    else if (idx < XC + WQC) { src = wq; dst = wqb; off = idx - XC; }
    else                     { src = wo; dst = wob; off = idx - XC - WQC; }
    float4 f = ((const float4*)src)[off];
    ushort4 o;
    o.x = f2bf(f.x); o.y = f2bf(f.y); o.z = f2bf(f.z); o.w = f2bf(f.w);
    ((ushort4*)dst)[off] = o;
  } else {
    int i2 = idx - TOTC;
    if (i2 < NB * 1024) {
      int b = i2 >> 10;
      int jj = (i2 & 1023) * 2;
      int Ls = ns_p[0];
      float4 o = make_float4(0.f, 0.f, 0.f, 0.f);
      if (jj < Ls) { o.x = positions[((size_t)b * Ls + jj) * 2];
                     o.y = positions[((size_t)b * Ls + jj) * 2 + 1]; }
      if (jj + 1 < Ls) { o.z = positions[((size_t)b * Ls + jj + 1) * 2];
                         o.w = positions[((size_t)b * Ls + jj + 1) * 2 + 1]; }
      *(float4*)&pospad[((size_t)b * NL + jj) * 2] = o;
    }
  }
}

// ---------------------------------------------------------------------------
// bf16 MTx128-tile MFMA GEMM, SWAPPED orientation: A = weights (M=out-dim),
// B = tokens (N=4096). C row (quad/reg) = out-dim -> vectorized epilogues.
// MODE 0 (MT=128): A=w_qkv[1536x512] -> q(pre-scaled)/k/v bf16 [b,h,l,dh].
// MODE 1 (MT=64):  A=w_out[512x512], B=attn -> f32 out[token][512] + bias.
// ---------------------------------------------------------------------------
template<int MODE, int MT>
__global__ __launch_bounds__(256, 2) void gemm_bf16(
    const unsigned short* __restrict__ A, const unsigned short* __restrict__ Bm,
    const float* __restrict__ bias,
    unsigned short* __restrict__ qo, unsigned short* __restrict__ ko,
    unsigned short* __restrict__ vo, float* __restrict__ out, int K)
{
  constexpr int MB = MT / 32;          // m-blocks per wave
  constexpr int AC = MT * 4;           // A-tile 16B chunks
  constexpr int TC = AC + 512;         // total chunks per K-step
  __shared__ __align__(16) unsigned short S[MT * 32 + 128 * 32];  // A | B
  const int tid = threadIdx.x, wid = tid >> 6, lane = tid & 63;
  const int quad = lane >> 4, l15 = lane & 15;
  const int m0 = blockIdx.x * MT, n0 = blockIdx.y * 128;
  const int wm = (wid >> 1) * (MT / 2), wn = (wid & 1) * 64;

  f32x4 acc[MB][4];
#pragma unroll
  for (int a = 0; a < MB; ++a)
#pragma unroll
    for (int b = 0; b < 4; ++b)
#pragma unroll
      for (int z = 0; z < 4; ++z) acc[a][b][z] = 0.f;

  for (int k0 = 0; k0 < K; k0 += 32) {
#pragma unroll
    for (int p = 0; p < TC / 256; ++p) {
      int c = p * 256 + wid * 64 + lane;   // lane-linear within wave
      if (c < AC) {
        int row = c >> 2, off = c & 3;
        gl_lds16(A + (size_t)(m0 + row) * K + k0 + off * 8, &S[c * 8]);
      } else {
        int cb = c - AC;
        int row = cb >> 2, off = cb & 3;
        gl_lds16(Bm + (size_t)(n0 + row) * K + k0 + off * 8, &S[c * 8]);
      }
    }
    __syncthreads();
    bf16x8 af[MB], bfr[4];
#pragma unroll
    for (int mb = 0; mb < MB; ++mb)
      af[mb] = *(const bf16x8*)&S[(wm + mb * 16 + l15) * 32 + quad * 8];
#pragma unroll
    for (int nb = 0; nb < 4; ++nb)
      bfr[nb] = *(const bf16x8*)&S[MT * 32 + (wn + nb * 16 + l15) * 32 + quad * 8];
#pragma unroll
    for (int mb = 0; mb < MB; ++mb)
#pragma unroll
      for (int nb = 0; nb < 4; ++nb)
        acc[mb][nb] = __builtin_amdgcn_mfma_f32_16x16x32_bf16(af[mb], bfr[nb], acc[mb][nb], 0, 0, 0);
    __syncthreads();
  }

  const float QSCALE = 0.125f * LOG2E;
#pragma unroll
  for (int mb = 0; mb < MB; ++mb) {
    int e0 = m0 + wm + mb * 16 + quad * 4;   // out-dim base for r=0..3
    if (MODE == 0) {
      int s   = e0 >> 9;          // wave-uniform: 0=q,1=k,2=v
      int hh  = (e0 >> 6) & 7;
      int dh0 = e0 & 63;
      unsigned short* dst = (s == 0) ? qo : ((s == 1) ? ko : vo);
      float sc = (s == 0) ? QSCALE : 1.0f;
#pragma unroll
      for (int nb = 0; nb < 4; ++nb) {
        int token = n0 + wn + nb * 16 + l15;
        int bb = token >> 11, ll = token & 2047;
        ushort4 o;
        o.x = f2bf(acc[mb][nb][0] * sc);
        o.y = f2bf(acc[mb][nb][1] * sc);
        o.z = f2bf(acc[mb][nb][2] * sc);
        o.w = f2bf(acc[mb][nb][3] * sc);
        *(ushort4*)&dst[(((size_t)bb * NH + hh) * NL + ll) * DH + dh0] = o;
      }
    } else {
      float4 bv = *(const float4*)&bias[e0];
#pragma unroll
      for (int nb = 0; nb < 4; ++nb) {
        int token = n0 + wn + nb * 16 + l15;
        float4 o;
        o.x = acc[mb][nb][0] + bv.x;
        o.y = acc[mb][nb][1] + bv.y;
        o.z = acc[mb][nb][2] + bv.z;
        o.w = acc[mb][nb][3] + bv.w;
        *(float4*)&out[(size_t)token * ND + e0] = o;
      }
    }
  }
}

// ---------------------------------------------------------------------------
// V transpose: [b,h,l,dh] -> [b,h,dh,l], LDS-tiled, coalesced both sides.
// ---------------------------------------------------------------------------
__global__ __launch_bounds__(256) void transpose_v(const unsigned short* __restrict__ v,
                                                   unsigned short* __restrict__ vT) {
  __shared__ unsigned short T[64][74];
  const int l0 = blockIdx.x * 64;
  const int bh = blockIdx.y;
  const unsigned short* src = v + ((size_t)bh * NL + l0) * DH;
  unsigned short* dst = vT + (size_t)bh * DH * NL;
#pragma unroll
  for (int p = 0; p < 2; ++p) {
    int c = p * 256 + threadIdx.x;
    int row = c >> 3, seg = c & 7;
    *(uint4*)&T[row][seg * 8] = *(const uint4*)(src + row * DH + seg * 8);
  }
  __syncthreads();
#pragma unroll
  for (int p = 0; p < 2; ++p) {
    int c = p * 256 + threadIdx.x;
    int drow = c >> 3, lseg = c & 7;
    unsigned short u[8];
#pragma unroll
    for (int z = 0; z < 8; ++z) u[z] = T[lseg * 8 + z][drow];
    *(uint4*)(dst + (size_t)drow * NL + l0 + lseg * 8) = *(uint4*)u;
  }
}

// ---------------------------------------------------------------------------
// Flash attention: S^T orientation + LDS-staged K/V^T tiles.
// Fixed-shift softmax, split-j=4 partials (1024 blocks = 4 blocks/CU).
// Block = 256 thr (4 waves), 128 q-rows/block (32/wave via l15, ib=2).
// accS = mfma(K_frag, Q_frag) => C col = i (lane), row = j (quad*4+reg):
//   P store = b64 vector writes, P re-load = b128 reads (wave-private).
// q pre-scaled by 0.125*log2e => S already in log2 domain.
// ---------------------------------------------------------------------------
__global__ __launch_bounds__(256, 4) void flash_kernel(
    const unsigned short* __restrict__ qb, const unsigned short* __restrict__ kb,
    const unsigned short* __restrict__ vTb, const float* __restrict__ pospad,
    const float* __restrict__ log_sigma, const float* __restrict__ gbias_p,
    const int* __restrict__ ns_p, float* __restrict__ Pbuf, float* __restrict__ rsbuf)
{
  const int it = blockIdx.x >> 2;       // 0..15
  const int js = blockIdx.x & 3;        // 0..3
  const int h  = blockIdx.y;
  const int b  = blockIdx.z;
  const int i0 = it * 128;
  const int jbase = js * (NL / JS);     // 512 j per block
  const int Ls = ns_p[0];
  const float gb  = gbias_p[0];
  const float sig = __expf(log_sigma[h]);
  const float CI  = LOG2E * 0.5f / (sig * sig);
  const float LGB = LOG2E * gb;
  const float CB  = -8.0f * LOG2E + LGB;   // fixed shift + global-bias floor

  const int tid  = threadIdx.x;
  const int wid  = tid >> 6;      // 0..3
  const int lane = tid & 63;
  const int quad = lane >> 4;
  const int l15  = lane & 15;

  __shared__ __align__(16) unsigned short Ks[64][72];           // [j][dh]
  __shared__ __align__(16) unsigned short Vt[64][72];           // [dh][j]
  __shared__ __align__(16) unsigned short Pls[4][2][16][72];    // [wave][ib][i][j]

  const size_t bh = (size_t)b * NH + h;
  const unsigned short* qbase  = qb  + (bh * NL + i0 + wid * 32) * DH;
  const unsigned short* kbase  = kb  + bh * NL * DH;
  const unsigned short* vtbase = vTb + bh * DH * NL;
  const float* posb = pospad + (size_t)b * NL * 2;

  // Q B-frags (lane = i) + i-side scalars
  bf16x8 qf[2][2];
  float pix[2], piy[2], ispf[2];
#pragma unroll
  for (int ib = 0; ib < 2; ++ib) {
#pragma unroll
    for (int kc = 0; kc < 2; ++kc)
      qf[ib][kc] = *(const bf16x8*)(qbase + (size_t)(ib * 16 + l15) * DH + kc * 32 + quad * 8);
    int ig = i0 + wid * 32 + ib * 16 + l15;
    float2 p2 = *(const float2*)(posb + (size_t)ig * 2);
    pix[ib] = p2.x; piy[ib] = p2.y;
    ispf[ib] = (ig < Ls) ? 1.f : 0.f;
  }

  f32x4 accO[4][2];   // [dhb][ib], O^T: row=dh(quad*4+r), col=i(l15)
  float rsum[2];
#pragma unroll
  for (int d = 0; d < 4; ++d)
#pragma unroll
    for (int ib = 0; ib < 2; ++ib)
#pragma unroll
      for (int z = 0; z < 4; ++z) accO[d][ib][z] = 0.f;
  rsum[0] = 0.f; rsum[1] = 0.f;

  // ---- register prefetch of tile 0 (coalesced) ----
  uint4 kr[2], vr[2];
  {
#pragma unroll
    for (int p = 0; p < 2; ++p) {
      int c = p * 256 + tid;          // 512 chunks: 64 rows x 8 segs of 16B
      int row = c >> 3, off = c & 7;
      kr[p] = *(const uint4*)(kbase  + (size_t)(jbase + row) * DH + off * 8);
      vr[p] = *(const uint4*)(vtbase + (size_t)row * NL + jbase + off * 8);
    }
  }

  for (int jt = 0; jt < NL / JS / 64; ++jt) {
    const int j0 = jbase + jt * 64;
    __syncthreads();   // prior iteration's LDS reads complete (+ drains prefetch vmcnt)

    // regs -> LDS (padded stride 72: balanced bank spread)
#pragma unroll
    for (int p = 0; p < 2; ++p) {
      int c = p * 256 + tid;
      int row = c >> 3, off = c & 7;
      *(uint4*)&Ks[row][off * 8] = kr[p];
      *(uint4*)&Vt[row][off * 8] = vr[p];
    }
    __syncthreads();

    // prefetch next tile (waited at next loop-top barrier)
    if (jt + 1 < NL / JS / 64) {
      const int jn = jbase + (jt + 1) * 64;
#pragma unroll
      for (int p = 0; p < 2; ++p) {
        int c = p * 256 + tid;
        int row = c >> 3, off = c & 7;
        kr[p] = *(const uint4*)(kbase  + (size_t)(jn + row) * DH + off * 8);
        vr[p] = *(const uint4*)(vtbase + (size_t)row * NL + jn + off * 8);
      }
    }

    // ---- K A-frags from LDS (b128 reads) ----
    bf16x8 kf[4][2];
#pragma unroll
    for (int jb = 0; jb < 4; ++jb)
#pragma unroll
      for (int kc = 0; kc < 2; ++kc)
        kf[jb][kc] = *(const bf16x8*)&Ks[jb * 16 + l15][kc * 32 + quad * 8];

    // ---- S^T = K Q^T ----
    f32x4 accS[4][2];
#pragma unroll
    for (int jb = 0; jb < 4; ++jb)
#pragma unroll
      for (int ib = 0; ib < 2; ++ib) {
#pragma unroll
        for (int z = 0; z < 4; ++z) accS[jb][ib][z] = 0.f;
        accS[jb][ib] = __builtin_amdgcn_mfma_f32_16x16x32_bf16(kf[jb][0], qf[ib][0], accS[jb][ib], 0, 0, 0);
        accS[jb][ib] = __builtin_amdgcn_mfma_f32_16x16x32_bf16(kf[jb][1], qf[ib][1], accS[jb][ib], 0, 0, 0);
      }

    // ---- bias + exp2 + P -> LDS (b64 vector writes) ----
#pragma unroll
    for (int jb = 0; jb < 4; ++jb) {
      int jrow = j0 + jb * 16 + quad * 4;
      float4 pA = *(const float4*)(posb + (size_t)jrow * 2);       // px0,py0,px1,py1
      float4 pB = *(const float4*)(posb + (size_t)jrow * 2 + 4);   // px2,py2,px3,py3
      float px[4] = {pA.x, pA.z, pB.x, pB.z};
      float py[4] = {pA.y, pA.w, pB.y, pB.w};
      float jok[4];
#pragma unroll
      for (int r = 0; r < 4; ++r) jok[r] = (jrow + r < Ls) ? 1.f : 0.f;
#pragma unroll
      for (int ib = 0; ib < 2; ++ib) {
        float p[4];
#pragma unroll
        for (int r = 0; r < 4; ++r) {
          float dx = pix[ib] - px[r];
          float dy = piy[ib] - py[r];
          float d2 = __builtin_fmaf(dx, dx, dy * dy);
          float u  = __builtin_fmaf(CI, d2, LGB);     // spatial-vs-global delta
          float m  = jok[r] * ispf[ib];
          float t  = __builtin_fmaf(-m, u, accS[jb][ib][r] + CB);
          p[r] = fexp2(t);
        }
        rsum[ib] += (p[0] + p[1]) + (p[2] + p[3]);
        uint2 w;
        w.x = (uint32_t)f2bf(p[0]) | ((uint32_t)f2bf(p[1]) << 16);
        w.y = (uint32_t)f2bf(p[2]) | ((uint32_t)f2bf(p[3]) << 16);
        *(uint2*)&Pls[wid][ib][l15][jb * 16 + quad * 4] = w;
      }
    }

    // ---- O^T += V^T P^T (wave-private Pls: no barrier; V A-frags from LDS) ----
    bf16x8 pbf[2][2];
#pragma unroll
    for (int ib = 0; ib < 2; ++ib)
#pragma unroll
      for (int pp = 0; pp < 2; ++pp)
        pbf[ib][pp] = *(const bf16x8*)&Pls[wid][ib][l15][pp * 32 + quad * 8];
#pragma unroll
    for (int dhb = 0; dhb < 4; ++dhb)
#pragma unroll
      for (int pp = 0; pp < 2; ++pp) {
        bf16x8 vf = *(const bf16x8*)&Vt[dhb * 16 + l15][pp * 32 + quad * 8];
#pragma unroll
        for (int ib = 0; ib < 2; ++ib)
          accO[dhb][ib] = __builtin_amdgcn_mfma_f32_16x16x32_bf16(vf, pbf[ib][pp], accO[dhb][ib], 0, 0, 0);
      }
  }

  // ---- epilogue: unnormalized partials ----
#pragma unroll
  for (int ib = 0; ib < 2; ++ib) {
    float v = rsum[ib];
    v += __shfl_xor(v, 16);
    v += __shfl_xor(v, 32);
    int ig = i0 + wid * 32 + ib * 16 + l15;
    if (quad == 0)
      rsbuf[(size_t)js * RG_TOT + bh * NL + ig] = v;
#pragma unroll
    for (int dhb = 0; dhb < 4; ++dhb) {
      float4 o;
      o.x = accO[dhb][ib][0]; o.y = accO[dhb][ib][1];
      o.z = accO[dhb][ib][2]; o.w = accO[dhb][ib][3];
      *(float4*)&Pbuf[((size_t)js * RG_TOT + bh * NL + ig) * DH + dhb * 16 + quad * 4] = o;
    }
  }
}

// ---------------------------------------------------------------------------
// Combine split-j partials (JS=4) -> bf16 attn [b, l, h*64+dh]
// ---------------------------------------------------------------------------
__global__ __launch_bounds__(256) void combine_kernel(const float* __restrict__ Pbuf,
                                                      const float* __restrict__ rsbuf,
                                                      unsigned short* __restrict__ attnb) {
  int idx = blockIdx.x * 256 + threadIdx.x;       // over RG_TOT*16 float4 chunks
  int rg = idx >> 4, c4 = idx & 15;
  const float4* p4 = (const float4*)Pbuf;
  float4 s = p4[(size_t)rg * 16 + c4];
  float rsum = rsbuf[rg];
#pragma unroll
  for (int js = 1; js < JS; ++js) {
    float4 p = p4[((size_t)js * RG_TOT + rg) * 16 + c4];
    s.x += p.x; s.y += p.y; s.z += p.z; s.w += p.w;
    rsum += rsbuf[(size_t)js * RG_TOT + rg];
  }
  float rs = 1.0f / rsum;
  int bhm = rg >> 11;           // b*8+h
  int l   = rg & 2047;
  int bb  = bhm >> 3, hh = bhm & 7;
  ushort4 o;
  o.x = f2bf(s.x * rs);
  o.y = f2bf(s.y * rs);
  o.z = f2bf(s.z * rs);
  o.w = f2bf(s.w * rs);
  *(ushort4*)&attnb[(((size_t)bb * NL + l) * ND) + hh * DH + c4 * 4] = o;
}

// ---------------------------------------------------------------------------
extern "C" void kernel_launch(void* const* d_in, const int* in_sizes, int n_in,
                              void* d_out, int out_size, void* d_ws, size_t ws_size,
                              hipStream_t stream) {
  const float* x         = (const float*)d_in[0];
  const float* positions = (const float*)d_in[1];
  const float* w_qkv     = (const float*)d_in[2];
  const float* w_out     = (const float*)d_in[3];
  const float* b_out     = (const float*)d_in[4];
  const float* log_sigma = (const float*)d_in[5];
  const float* gbias     = (const float*)d_in[6];
  const int*   ns        = (const int*)d_in[7];

  // workspace layout with lifetime-based overlap:
  //   fixed:  xb | wob | qbf | kbf | vTf | pospad
  //   region R (reused): [wqb | vbf]  overlapped by  [Pbuf | rsbuf]
  //   (wqb dead after gemm1, vbf dead after transpose; Pbuf written by flash)
  unsigned short* ws  = (unsigned short*)d_ws;
  unsigned short* xb  = ws;                    // 2,097,152 shorts (reused as attn bf16)
  unsigned short* wob = xb  + 2097152;         //   262,144
  unsigned short* qbf = wob + 262144;          // 2,097,152
  unsigned short* kbf = qbf + 2097152;         // 2,097,152
  unsigned short* vTf = kbf + 2097152;         // 2,097,152
  float* pospad = (float*)(vTf + 2097152);     // NB*2048*2 f32 = 8192
  unsigned short* R   = (unsigned short*)(pospad + NB * NL * 2);
  unsigned short* wqb = R;                     //   786,432 shorts
  unsigned short* vbf = R + 786432;            // 2,097,152 shorts
  float* Pbuf  = (float*)R;                    // JS * 32768 * 64 f32 = 33.5 MB
  float* rsbuf = Pbuf + (size_t)JS * RG_TOT * DH;  // JS * 32768 f32

  // 1) f32 -> bf16 + padded positions
  cvt_f32_bf16<<<(TOTC + NB * 1024 + 255) / 256, 256, 0, stream>>>(
      x, w_qkv, w_out, positions, ns, xb, wqb, wob, pospad);

  // 2) QKV projection (swapped: A=w_qkv rows, B=token rows) -> q(scaled), k, v
  dim3 g1((3 * NH * DH) / 128, NB * NL / 128);
  gemm_bf16<0, 128><<<g1, 256, 0, stream>>>(wqb, xb, nullptr, qbf, kbf, vbf, nullptr, ND);

  // 3) V transpose -> [b,h,dh,l]
  dim3 gt(NL / 64, NB * NH);
  transpose_v<<<gt, 256, 0, stream>>>(vbf, vTf);

  // 4) flash attention partials (split-j=4, 1024 blocks = 4/CU)
  dim3 g2((NL / 128) * JS, NH, NB);
  flash_kernel<<<g2, 256, 0, stream>>>(qbf, kbf, vTf, pospad, log_sigma, gbias, ns,
                                       Pbuf, rsbuf);

  // 5) combine -> bf16 attn (into xb)
  combine_kernel<<<RG_TOT * 16 / 256, 256, 0, stream>>>(Pbuf, rsbuf, xb);

  // 6) output projection (swapped, 64-row M-tiles: 256 blocks) + bias -> f32
  dim3 g3(ND / 64, NB * NL / 128);
  gemm_bf16<1, 64><<<g3, 256, 0, stream>>>(wob, xb, b_out, nullptr, nullptr, nullptr,
                                           (float*)d_out, NH * DH);
}

// Round 7
// 169.849 us; speedup vs baseline: 1.1691x; 1.1691x over previous
//
#include <hip/hip_runtime.h>
#include <stdint.h>
#include <stddef.h>

// Problem constants (fixed by setup_inputs)
#define NB   2      // batch
#define NL   2048   // seq len
#define ND   512    // model dim
#define NH   8      // heads
#define DH   64     // dim head
#define LOG2E 1.44269504f
#define NIT  16     // i-tiles (128 rows each)
#define RG_TOT 32768  // NB*NH*NL rows of partials
#define JS   4      // split-j factor

typedef __attribute__((ext_vector_type(8))) short bf16x8;
typedef __attribute__((ext_vector_type(4))) float f32x4;

__device__ __forceinline__ unsigned short f2bf(float f) {
  union { float f; unsigned int u; } c; c.f = f;
  unsigned int u = c.u;
  unsigned int r = u + 0x7fffu + ((u >> 16) & 1u);
  return (unsigned short)(r >> 16);
}

__device__ __forceinline__ float bf2f(unsigned short u) {
  union { unsigned int i; float f; } c; c.i = ((unsigned int)u) << 16; return c.f;
}

__device__ __forceinline__ float fexp2(float x) {
#if __has_builtin(__builtin_amdgcn_exp2f)
  return __builtin_amdgcn_exp2f(x);
#else
  return exp2f(x);
#endif
}

// async global->LDS 16B copy; lanes of a wave must target base + lane*16
__device__ __forceinline__ void gl_lds16(const unsigned short* g, unsigned short* l) {
#if __has_builtin(__builtin_amdgcn_global_load_lds)
  __builtin_amdgcn_global_load_lds(
      (const __attribute__((address_space(1))) unsigned int*)g,
      (__attribute__((address_space(3))) unsigned int*)l, 16, 0, 0);
#else
  *(uint4*)l = *(const uint4*)g;
#endif
}

// ---------------------------------------------------------------------------
// f32 -> bf16 conversion for x, w_qkv, w_out (flat grid over float4 chunks)
// ---------------------------------------------------------------------------
#define XC  524288   // 4096*512/4
#define WQC 196608   // 1536*512/4
#define WOC 65536    // 512*512/4
#define TOTC (XC + WQC + WOC)
__global__ void cvt_f32_bf16(const float* __restrict__ x, const float* __restrict__ wq,
                             const float* __restrict__ wo, unsigned short* __restrict__ xb,
                             unsigned short* __restrict__ wqb, unsigned short* __restrict__ wob) {
  int idx = blockIdx.x * 256 + threadIdx.x;
  const float* src; unsigned short* dst; int off;
  if (idx < XC)            { src = x;  dst = xb;  off = idx; }
  else if (idx < XC + WQC) { src = wq; dst = wqb; off = idx - XC; }
  else                     { src = wo; dst = wob; off = idx - XC - WQC; }
  float4 f = ((const float4*)src)[off];
  ushort4 o;
  o.x = f2bf(f.x); o.y = f2bf(f.y); o.z = f2bf(f.z); o.w = f2bf(f.w);
  ((ushort4*)dst)[off] = o;
}

// ---------------------------------------------------------------------------
// bf16 MTx128-tile MFMA GEMM, SWAPPED orientation: A = weights (M=out-dim),
// B = tokens (N=4096). C row (quad/reg) = out-dim -> vectorized epilogues.
// MODE 0 (MT=128): A=w_qkv -> q(pre-scaled)/k row-major [b,h,l,dh] (ushort4)
//                  and v TRANSPOSED [b,h,dh,l] (fused transpose, scalar st).
// MODE 1 (MT=64):  A=w_out, B=attn -> f32 out[token][512] + bias (float4).
// ---------------------------------------------------------------------------
template<int MODE, int MT>
__global__ __launch_bounds__(256, 2) void gemm_bf16(
    const unsigned short* __restrict__ A, const unsigned short* __restrict__ Bm,
    const float* __restrict__ bias,
    unsigned short* __restrict__ qo, unsigned short* __restrict__ ko,
    unsigned short* __restrict__ vTo, float* __restrict__ out, int K)
{
  constexpr int MB = MT / 32;          // m-blocks per wave
  constexpr int AC = MT * 4;           // A-tile 16B chunks
  constexpr int TC = AC + 512;         // total chunks per K-step
  __shared__ __align__(16) unsigned short S[MT * 32 + 128 * 32];  // A | B
  const int tid = threadIdx.x, wid = tid >> 6, lane = tid & 63;
  const int quad = lane >> 4, l15 = lane & 15;
  const int m0 = blockIdx.x * MT, n0 = blockIdx.y * 128;
  const int wm = (wid >> 1) * (MT / 2), wn = (wid & 1) * 64;

  f32x4 acc[MB][4];
#pragma unroll
  for (int a = 0; a < MB; ++a)
#pragma unroll
    for (int b = 0; b < 4; ++b)
#pragma unroll
      for (int z = 0; z < 4; ++z) acc[a][b][z] = 0.f;

  for (int k0 = 0; k0 < K; k0 += 32) {
#pragma unroll
    for (int p = 0; p < TC / 256; ++p) {
      int c = p * 256 + wid * 64 + lane;   // lane-linear within wave
      if (c < AC) {
        int row = c >> 2, off = c & 3;
        gl_lds16(A + (size_t)(m0 + row) * K + k0 + off * 8, &S[c * 8]);
      } else {
        int cb = c - AC;
        int row = cb >> 2, off = cb & 3;
        gl_lds16(Bm + (size_t)(n0 + row) * K + k0 + off * 8, &S[c * 8]);
      }
    }
    __syncthreads();
    bf16x8 af[MB], bfr[4];
#pragma unroll
    for (int mb = 0; mb < MB; ++mb)
      af[mb] = *(const bf16x8*)&S[(wm + mb * 16 + l15) * 32 + quad * 8];
#pragma unroll
    for (int nb = 0; nb < 4; ++nb)
      bfr[nb] = *(const bf16x8*)&S[MT * 32 + (wn + nb * 16 + l15) * 32 + quad * 8];
#pragma unroll
    for (int mb = 0; mb < MB; ++mb)
#pragma unroll
      for (int nb = 0; nb < 4; ++nb)
        acc[mb][nb] = __builtin_amdgcn_mfma_f32_16x16x32_bf16(af[mb], bfr[nb], acc[mb][nb], 0, 0, 0);
    __syncthreads();
  }

  const float QSCALE = 0.125f * LOG2E;
#pragma unroll
  for (int mb = 0; mb < MB; ++mb) {
    int e0 = m0 + wm + mb * 16 + quad * 4;   // out-dim base for r=0..3
    if (MODE == 0) {
      int s   = e0 >> 9;          // block-uniform: 0=q,1=k,2=v
      int hh  = (e0 >> 6) & 7;
      int dh0 = e0 & 63;
      if (s < 2) {
        unsigned short* dst = (s == 0) ? qo : ko;
        float sc = (s == 0) ? QSCALE : 1.0f;
#pragma unroll
        for (int nb = 0; nb < 4; ++nb) {
          int token = n0 + wn + nb * 16 + l15;
          int bb = token >> 11, ll = token & 2047;
          ushort4 o;
          o.x = f2bf(acc[mb][nb][0] * sc);
          o.y = f2bf(acc[mb][nb][1] * sc);
          o.z = f2bf(acc[mb][nb][2] * sc);
          o.w = f2bf(acc[mb][nb][3] * sc);
          *(ushort4*)&dst[(((size_t)bb * NH + hh) * NL + ll) * DH + dh0] = o;
        }
      } else {
        // fused V transpose: vT[b][h][dh][l]  (16 contiguous shorts per quad)
#pragma unroll
        for (int nb = 0; nb < 4; ++nb) {
          int token = n0 + wn + nb * 16 + l15;
          int bb = token >> 11, ll = token & 2047;
          size_t base = ((size_t)bb * NH + hh) * DH * NL + ll;
#pragma unroll
          for (int r = 0; r < 4; ++r)
            vTo[base + (size_t)(dh0 + r) * NL] = f2bf(acc[mb][nb][r]);
        }
      }
    } else {
      float4 bv = *(const float4*)&bias[e0];
#pragma unroll
      for (int nb = 0; nb < 4; ++nb) {
        int token = n0 + wn + nb * 16 + l15;
        float4 o;
        o.x = acc[mb][nb][0] + bv.x;
        o.y = acc[mb][nb][1] + bv.y;
        o.z = acc[mb][nb][2] + bv.z;
        o.w = acc[mb][nb][3] + bv.w;
        *(float4*)&out[(size_t)token * ND + e0] = o;
      }
    }
  }
}

// ---------------------------------------------------------------------------
// Flash attention (R3-proven structure), fixed-shift softmax, split-j=JS
// partials. Block = 256 thr (4 waves); 128 q-rows/block (32/wave, 2 m-blocks).
// NOTE: launch_bounds(256,2) — do NOT force 4 waves/EU (R6 showed it spills
// ~150 live regs into scratch => 182 MB of HBM scratch traffic).
// Writes UNNORMALIZED accO as bf16 + f32 row sums; combine merges JS slices.
// q pre-scaled by 0.125*log2e => S already in log2 domain.
// ---------------------------------------------------------------------------
__global__ __launch_bounds__(256, 2) void flash_kernel(
    const unsigned short* __restrict__ qb, const unsigned short* __restrict__ kb,
    const unsigned short* __restrict__ vTb, const float* __restrict__ positions,
    const float* __restrict__ log_sigma, const float* __restrict__ gbias_p,
    const int* __restrict__ ns_p, unsigned short* __restrict__ Pb, float* __restrict__ rsbuf)
{
  const int it = blockIdx.x >> 2;       // 0..15
  const int js = blockIdx.x & 3;        // 0..3
  const int h  = blockIdx.y;
  const int b  = blockIdx.z;
  const int i0 = it * 128;
  const int jbase = js * (NL / JS);     // 512 j per block
  const int Ls = ns_p[0];
  const float gb = gbias_p[0];
  const float sig = __expf(log_sigma[h]);
  const float CI = LOG2E * 0.5f / (sig * sig);
  const float A2 = 2.0f * CI;
  const float CG = LOG2E * gb * 0.5f;
  const float C8N = -8.0f * LOG2E;

  const int tid  = threadIdx.x;
  const int wid  = tid >> 6;      // 0..3
  const int lane = tid & 63;
  const int quad = lane >> 4;
  const int l15  = lane & 15;

  __shared__ __align__(16) unsigned short Ks[64][72];
  __shared__ __align__(16) unsigned short Vt[64][72];   // [dh][j]
  __shared__ __align__(16) unsigned short Ps[128][72];
  __shared__ __align__(16) float4 pjc[64];              // {A2*pjx, A2*pjy, rjCm, 0}

  const size_t bh = (size_t)b * NH + h;
  const unsigned short* qbase  = qb  + (bh * NL + i0) * DH;
  const unsigned short* kbase  = kb  + bh * NL * DH;
  const unsigned short* vtbase = vTb + bh * DH * NL;

  // hoisted Q fragments: rows wid*32 + mb*16 + l15
  bf16x8 af[2][2];
#pragma unroll
  for (int mb = 0; mb < 2; ++mb)
#pragma unroll
    for (int kc = 0; kc < 2; ++kc)
      af[mb][kc] = *(const bf16x8*)(qbase + (size_t)(wid * 32 + mb * 16 + l15) * DH + kc * 32 + quad * 8);

  // i-side per-row constants
  float pix_[2][4], piy_[2][4], riCm[2][4], ispf[2][4];
#pragma unroll
  for (int mb = 0; mb < 2; ++mb)
#pragma unroll
    for (int r = 0; r < 4; ++r) {
      int ig = i0 + wid * 32 + mb * 16 + quad * 4 + r;
      float px = 0.f, py = 0.f, sf = 0.f, rc = 0.f;
      if (ig < Ls) {
        float2 p2 = *(const float2*)(positions + ((size_t)b * Ls + ig) * 2);
        px = p2.x; py = p2.y; sf = 1.f;
        rc = -(CI * (px * px + py * py)) - CG;
      }
      pix_[mb][r] = px; piy_[mb][r] = py; ispf[mb][r] = sf; riCm[mb][r] = rc;
    }

  f32x4 accO[2][4];
  float rsum[2][4];
#pragma unroll
  for (int mb = 0; mb < 2; ++mb) {
#pragma unroll
    for (int nb = 0; nb < 4; ++nb)
#pragma unroll
      for (int z = 0; z < 4; ++z) accO[mb][nb][z] = 0.f;
#pragma unroll
    for (int r = 0; r < 4; ++r) rsum[mb][r] = 0.f;
  }

  // ---- register prefetch of tile 0 ----
  uint4 kr[2], vr[2];
  float2 pr = make_float2(0.f, 0.f);
  {
#pragma unroll
    for (int p = 0; p < 2; ++p) {
      int c = p * 256 + tid;          // 512 chunks: 64 rows x 8 segs
      int row = c >> 3, off = c & 7;
      kr[p] = *(const uint4*)(kbase  + (size_t)(jbase + row) * DH + off * 8);
      vr[p] = *(const uint4*)(vtbase + (size_t)row * NL + jbase + off * 8);
    }
    if (tid < 64 && (jbase + tid) < Ls)
      pr = *(const float2*)(positions + ((size_t)b * Ls + jbase + tid) * 2);
  }

  for (int jt = 0; jt < NL / JS / 64; ++jt) {
    const int j0 = jbase + jt * 64;
    __syncthreads();

    // regs -> LDS
#pragma unroll
    for (int p = 0; p < 2; ++p) {
      int c = p * 256 + tid;
      int row = c >> 3, off = c & 7;
      *(uint4*)&Ks[row][off * 8] = kr[p];
      *(uint4*)&Vt[row][off * 8] = vr[p];
    }
    if (tid < 64) {
      bool jsp = (j0 + tid) < Ls;
      float px = jsp ? pr.x : 0.f, py = jsp ? pr.y : 0.f;
      float rc = jsp ? (-(CI * (px * px + py * py)) - CG) : 0.f;
      pjc[tid] = make_float4(A2 * px, A2 * py, rc, 0.f);
    }
    __syncthreads();

    // prefetch next tile
    if (jt + 1 < NL / JS / 64) {
      const int jn = jbase + (jt + 1) * 64;
#pragma unroll
      for (int p = 0; p < 2; ++p) {
        int c = p * 256 + tid;
        int row = c >> 3, off = c & 7;
        kr[p] = *(const uint4*)(kbase  + (size_t)(jn + row) * DH + off * 8);
        vr[p] = *(const uint4*)(vtbase + (size_t)row * NL + jn + off * 8);
      }
      if (tid < 64 && (jn + tid) < Ls)
        pr = *(const float2*)(positions + ((size_t)b * Ls + jn + tid) * 2);
    }

    // ---- S = Q' K^T ----
    f32x4 accS[2][4];
#pragma unroll
    for (int mb = 0; mb < 2; ++mb)
#pragma unroll
      for (int nb = 0; nb < 4; ++nb)
#pragma unroll
        for (int z = 0; z < 4; ++z) accS[mb][nb][z] = 0.f;
#pragma unroll
    for (int nb = 0; nb < 4; ++nb) {
      bf16x8 b0 = *(const bf16x8*)&Ks[nb * 16 + l15][quad * 8];
      bf16x8 b1 = *(const bf16x8*)&Ks[nb * 16 + l15][32 + quad * 8];
#pragma unroll
      for (int mb = 0; mb < 2; ++mb) {
        accS[mb][nb] = __builtin_amdgcn_mfma_f32_16x16x32_bf16(af[mb][0], b0, accS[mb][nb], 0, 0, 0);
        accS[mb][nb] = __builtin_amdgcn_mfma_f32_16x16x32_bf16(af[mb][1], b1, accS[mb][nb], 0, 0, 0);
      }
    }

    // ---- bias + exp2 + P store ----
    float4 pc[4]; float jspf_[4];
#pragma unroll
    for (int nb = 0; nb < 4; ++nb) {
      pc[nb] = pjc[nb * 16 + l15];
      jspf_[nb] = ((j0 + nb * 16 + l15) < Ls) ? 1.f : 0.f;
    }
#pragma unroll
    for (int mb = 0; mb < 2; ++mb)
#pragma unroll
      for (int nb = 0; nb < 4; ++nb)
#pragma unroll
        for (int r = 0; r < 4; ++r) {
          float t = accS[mb][nb][r] + C8N;
          t = __builtin_fmaf(ispf[mb][r], pc[nb].z, t);
          t = __builtin_fmaf(jspf_[nb], riCm[mb][r], t);
          t = __builtin_fmaf(piy_[mb][r], pc[nb].y, t);
          t = __builtin_fmaf(pix_[mb][r], pc[nb].x, t);
          float p = fexp2(t);
          rsum[mb][r] += p;
          Ps[wid * 32 + mb * 16 + quad * 4 + r][nb * 16 + l15] = f2bf(p);
        }

    // ---- O += P V (Ps rows are wave-private) ----
    bf16x8 pf[2][2];
#pragma unroll
    for (int mb = 0; mb < 2; ++mb) {
      pf[mb][0] = *(const bf16x8*)&Ps[wid * 32 + mb * 16 + l15][quad * 8];
      pf[mb][1] = *(const bf16x8*)&Ps[wid * 32 + mb * 16 + l15][32 + quad * 8];
    }
#pragma unroll
    for (int nb = 0; nb < 4; ++nb) {
      bf16x8 v0 = *(const bf16x8*)&Vt[nb * 16 + l15][quad * 8];
      bf16x8 v1 = *(const bf16x8*)&Vt[nb * 16 + l15][32 + quad * 8];
#pragma unroll
      for (int mb = 0; mb < 2; ++mb) {
        accO[mb][nb] = __builtin_amdgcn_mfma_f32_16x16x32_bf16(pf[mb][0], v0, accO[mb][nb], 0, 0, 0);
        accO[mb][nb] = __builtin_amdgcn_mfma_f32_16x16x32_bf16(pf[mb][1], v1, accO[mb][nb], 0, 0, 0);
      }
    }
  }

  // ---- epilogue: store UNNORMALIZED partials (bf16 accO, f32 rsum) ----
#pragma unroll
  for (int mb = 0; mb < 2; ++mb)
#pragma unroll
    for (int r = 0; r < 4; ++r) {
      float v = rsum[mb][r];
      v += __shfl_xor(v, 1);
      v += __shfl_xor(v, 2);
      v += __shfl_xor(v, 4);
      v += __shfl_xor(v, 8);
      rsum[mb][r] = v;
    }
  const size_t rgbase = (bh * NIT + it) * 128;
  const size_t poff = (size_t)js * RG_TOT * DH;
#pragma unroll
  for (int mb = 0; mb < 2; ++mb)
#pragma unroll
    for (int r = 0; r < 4; ++r) {
      int row = wid * 32 + mb * 16 + quad * 4 + r;
#pragma unroll
      for (int nb = 0; nb < 4; ++nb)
        Pb[poff + (rgbase + row) * DH + nb * 16 + l15] = f2bf(accO[mb][nb][r]);
      if (l15 == 0)
        rsbuf[(size_t)js * RG_TOT + rgbase + row] = rsum[mb][r];
    }
}

// ---------------------------------------------------------------------------
// Combine split-j partials (JS, bf16) -> bf16 attn [b, l, h*64+dh]
// ---------------------------------------------------------------------------
__global__ __launch_bounds__(256) void combine_kernel(const unsigned short* __restrict__ Pb,
                                                      const float* __restrict__ rsbuf,
                                                      unsigned short* __restrict__ attnb) {
  int idx = blockIdx.x * 256 + threadIdx.x;       // over RG_TOT*16 ushort4 chunks
  int rg = idx >> 4, c4 = idx & 15;
  float s0 = 0.f, s1 = 0.f, s2 = 0.f, s3 = 0.f, rsum = 0.f;
#pragma unroll
  for (int js = 0; js < JS; ++js) {
    ushort4 u = *(const ushort4*)&Pb[((size_t)js * RG_TOT + rg) * DH + c4 * 4];
    s0 += bf2f(u.x); s1 += bf2f(u.y); s2 += bf2f(u.z); s3 += bf2f(u.w);
    rsum += rsbuf[(size_t)js * RG_TOT + rg];
  }
  float rs = 1.0f / rsum;
  int bhm = rg >> 11;           // b*8+h
  int l   = rg & 2047;
  int bb  = bhm >> 3, hh = bhm & 7;
  ushort4 o;
  o.x = f2bf(s0 * rs);
  o.y = f2bf(s1 * rs);
  o.z = f2bf(s2 * rs);
  o.w = f2bf(s3 * rs);
  *(ushort4*)&attnb[(((size_t)bb * NL + l) * ND) + hh * DH + c4 * 4] = o;
}

// ---------------------------------------------------------------------------
extern "C" void kernel_launch(void* const* d_in, const int* in_sizes, int n_in,
                              void* d_out, int out_size, void* d_ws, size_t ws_size,
                              hipStream_t stream) {
  const float* x         = (const float*)d_in[0];
  const float* positions = (const float*)d_in[1];
  const float* w_qkv     = (const float*)d_in[2];
  const float* w_out     = (const float*)d_in[3];
  const float* b_out     = (const float*)d_in[4];
  const float* log_sigma = (const float*)d_in[5];
  const float* gbias     = (const float*)d_in[6];
  const int*   ns        = (const int*)d_in[7];

  // workspace layout (shorts unless noted); lifetime overlap:
  //   region R: [wqb] (dead after gemm1)  overlapped by  [Pb | rsbuf] (flash)
  unsigned short* ws  = (unsigned short*)d_ws;
  unsigned short* xb  = ws;                    // 2,097,152 (reused as attn bf16)
  unsigned short* wob = xb  + 2097152;         //   262,144
  unsigned short* qbf = wob + 262144;          // 2,097,152
  unsigned short* kbf = qbf + 2097152;         // 2,097,152
  unsigned short* vTf = kbf + 2097152;         // 2,097,152
  unsigned short* R   = vTf + 2097152;
  unsigned short* wqb = R;                     //   786,432 shorts
  unsigned short* Pb  = R;                     // JS*32768*64 bf16 = 16.8 MB
  float* rsbuf = (float*)(Pb + (size_t)JS * RG_TOT * DH);  // JS*32768 f32

  // 1) f32 -> bf16
  cvt_f32_bf16<<<TOTC / 256, 256, 0, stream>>>(x, w_qkv, w_out, xb, wqb, wob);

  // 2) QKV projection -> q(scaled), k row-major; v transposed (fused)
  dim3 g1((3 * NH * DH) / 128, NB * NL / 128);
  gemm_bf16<0, 128><<<g1, 256, 0, stream>>>(wqb, xb, nullptr, qbf, kbf, vTf, nullptr, ND);

  // 3) flash attention partials (split-j=4, 1024 blocks; natural VGPR alloc)
  dim3 g2((NL / 128) * JS, NH, NB);
  flash_kernel<<<g2, 256, 0, stream>>>(qbf, kbf, vTf, positions, log_sigma, gbias, ns,
                                       Pb, rsbuf);

  // 4) combine -> bf16 attn (into xb)
  combine_kernel<<<RG_TOT * 16 / 256, 256, 0, stream>>>(Pb, rsbuf, xb);

  // 5) output projection (64-row M-tiles: 256 blocks) + bias -> f32 d_out
  dim3 g3(ND / 64, NB * NL / 128);
  gemm_bf16<1, 64><<<g3, 256, 0, stream>>>(wob, xb, b_out, nullptr, nullptr, nullptr,
                                           (float*)d_out, NH * DH);
}

// Round 8
// 154.197 us; speedup vs baseline: 1.2878x; 1.1015x over previous
//
#include <hip/hip_runtime.h>
#include <stdint.h>
#include <stddef.h>

// Problem constants (fixed by setup_inputs)
#define NB   2      // batch
#define NL   2048   // seq len
#define ND   512    // model dim
#define NH   8      // heads
#define DH   64     // dim head
#define LOG2E 1.44269504f
#define NIT  16     // i-tiles (128 rows each)
#define RG_TOT 32768  // NB*NH*NL rows of partials
#define JS   4      // split-j factor

typedef __attribute__((ext_vector_type(8))) short bf16x8;
typedef __attribute__((ext_vector_type(4))) float f32x4;

__device__ __forceinline__ unsigned short f2bf(float f) {
  union { float f; unsigned int u; } c; c.f = f;
  unsigned int u = c.u;
  unsigned int r = u + 0x7fffu + ((u >> 16) & 1u);
  return (unsigned short)(r >> 16);
}

__device__ __forceinline__ float bf2f(unsigned short u) {
  union { unsigned int i; float f; } c; c.i = ((unsigned int)u) << 16; return c.f;
}

__device__ __forceinline__ float fexp2(float x) {
#if __has_builtin(__builtin_amdgcn_exp2f)
  return __builtin_amdgcn_exp2f(x);
#else
  return exp2f(x);
#endif
}

// async global->LDS 16B copy; lanes of a wave must target base + lane*16
__device__ __forceinline__ void gl_lds16(const unsigned short* g, unsigned short* l) {
#if __has_builtin(__builtin_amdgcn_global_load_lds)
  __builtin_amdgcn_global_load_lds(
      (const __attribute__((address_space(1))) unsigned int*)g,
      (__attribute__((address_space(3))) unsigned int*)l, 16, 0, 0);
#else
  *(uint4*)l = *(const uint4*)g;
#endif
}

// ---------------------------------------------------------------------------
// f32 -> bf16 conversion for x, w_qkv, w_out + zero-padded positions buffer
// ---------------------------------------------------------------------------
#define XC  524288   // 4096*512/4
#define WQC 196608   // 1536*512/4
#define WOC 65536    // 512*512/4
#define TOTC (XC + WQC + WOC)
__global__ void cvt_f32_bf16(const float* __restrict__ x, const float* __restrict__ wq,
                             const float* __restrict__ wo, const float* __restrict__ positions,
                             const int* __restrict__ ns_p,
                             unsigned short* __restrict__ xb, unsigned short* __restrict__ wqb,
                             unsigned short* __restrict__ wob, float* __restrict__ pospad) {
  int idx = blockIdx.x * 256 + threadIdx.x;
  if (idx < TOTC) {
    const float* src; unsigned short* dst; int off;
    if (idx < XC)            { src = x;  dst = xb;  off = idx; }
    else if (idx < XC + WQC) { src = wq; dst = wqb; off = idx - XC; }
    else                     { src = wo; dst = wob; off = idx - XC - WQC; }
    float4 f = ((const float4*)src)[off];
    ushort4 o;
    o.x = f2bf(f.x); o.y = f2bf(f.y); o.z = f2bf(f.z); o.w = f2bf(f.w);
    ((ushort4*)dst)[off] = o;
  } else {
    int i2 = idx - TOTC;
    if (i2 < NB * 1024) {
      int b = i2 >> 10;
      int jj = (i2 & 1023) * 2;
      int Ls = ns_p[0];
      float4 o = make_float4(0.f, 0.f, 0.f, 0.f);
      if (jj < Ls) { o.x = positions[((size_t)b * Ls + jj) * 2];
                     o.y = positions[((size_t)b * Ls + jj) * 2 + 1]; }
      if (jj + 1 < Ls) { o.z = positions[((size_t)b * Ls + jj + 1) * 2];
                         o.w = positions[((size_t)b * Ls + jj + 1) * 2 + 1]; }
      *(float4*)&pospad[((size_t)b * NL + jj) * 2] = o;
    }
  }
}

// ---------------------------------------------------------------------------
// bf16 MTx128-tile MFMA GEMM, SWAPPED orientation: A = weights (M=out-dim),
// B = tokens (N=4096). C row (quad/reg) = out-dim.
// MODE 0 (MT=128): A=w_qkv ->
//   q: pre-scaled, row-major [b,h,l,dh] (ushort4)
//   k: FRAGMENT-MAJOR K' blocks: ((bh*128 + jt)*2 + kc)*512 + lane*8 shorts,
//      where lane=(q_t,l15) holds K[jt*16+l15][kc*32 + q_t*8 .. +8]  (ushort4)
//   v: row-major [b,h,l,dh] (ushort4) -> repack_v makes V'
// MODE 1 (MT=64): A=w_out, B=attn -> f32 out[token][512] + bias (float4).
// ---------------------------------------------------------------------------
template<int MODE, int MT>
__global__ __launch_bounds__(256, 2) void gemm_bf16(
    const unsigned short* __restrict__ A, const unsigned short* __restrict__ Bm,
    const float* __restrict__ bias,
    unsigned short* __restrict__ qo, unsigned short* __restrict__ kp,
    unsigned short* __restrict__ vo, float* __restrict__ out, int K)
{
  constexpr int MB = MT / 32;          // m-blocks per wave
  constexpr int AC = MT * 4;           // A-tile 16B chunks
  constexpr int TC = AC + 512;         // total chunks per K-step
  __shared__ __align__(16) unsigned short S[MT * 32 + 128 * 32];  // A | B
  const int tid = threadIdx.x, wid = tid >> 6, lane = tid & 63;
  const int quad = lane >> 4, l15 = lane & 15;
  const int m0 = blockIdx.x * MT, n0 = blockIdx.y * 128;
  const int wm = (wid >> 1) * (MT / 2), wn = (wid & 1) * 64;

  f32x4 acc[MB][4];
#pragma unroll
  for (int a = 0; a < MB; ++a)
#pragma unroll
    for (int b = 0; b < 4; ++b)
#pragma unroll
      for (int z = 0; z < 4; ++z) acc[a][b][z] = 0.f;

  for (int k0 = 0; k0 < K; k0 += 32) {
#pragma unroll
    for (int p = 0; p < TC / 256; ++p) {
      int c = p * 256 + wid * 64 + lane;   // lane-linear within wave
      if (c < AC) {
        int row = c >> 2, off = c & 3;
        gl_lds16(A + (size_t)(m0 + row) * K + k0 + off * 8, &S[c * 8]);
      } else {
        int cb = c - AC;
        int row = cb >> 2, off = cb & 3;
        gl_lds16(Bm + (size_t)(n0 + row) * K + k0 + off * 8, &S[c * 8]);
      }
    }
    __syncthreads();
    bf16x8 af[MB], bfr[4];
#pragma unroll
    for (int mb = 0; mb < MB; ++mb)
      af[mb] = *(const bf16x8*)&S[(wm + mb * 16 + l15) * 32 + quad * 8];
#pragma unroll
    for (int nb = 0; nb < 4; ++nb)
      bfr[nb] = *(const bf16x8*)&S[MT * 32 + (wn + nb * 16 + l15) * 32 + quad * 8];
#pragma unroll
    for (int mb = 0; mb < MB; ++mb)
#pragma unroll
      for (int nb = 0; nb < 4; ++nb)
        acc[mb][nb] = __builtin_amdgcn_mfma_f32_16x16x32_bf16(af[mb], bfr[nb], acc[mb][nb], 0, 0, 0);
    __syncthreads();
  }

  const float QSCALE = 0.125f * LOG2E;
#pragma unroll
  for (int mb = 0; mb < MB; ++mb) {
    int e0 = m0 + wm + mb * 16 + quad * 4;   // out-dim base for r=0..3
    if (MODE == 0) {
      int s   = e0 >> 9;          // wave-uniform: 0=q,1=k,2=v
      int hh  = (e0 >> 6) & 7;
      if (s == 1) {
        // fragment-major K'
        int kc  = mb >> 1;                         // dh chunk of 32
        int q_t = ((mb & 1) << 1) + (quad >> 1);   // target quad
        int par = quad & 1;                        // 4-short sub-offset
#pragma unroll
        for (int nb = 0; nb < 4; ++nb) {
          int token = n0 + wn + nb * 16 + l15;
          int bb = token >> 11, ll = token & 2047;
          int jt = ll >> 4;
          ushort4 o;
          o.x = f2bf(acc[mb][nb][0]);
          o.y = f2bf(acc[mb][nb][1]);
          o.z = f2bf(acc[mb][nb][2]);
          o.w = f2bf(acc[mb][nb][3]);
          size_t addr = (((size_t)(bb * NH + hh) * 128 + jt) * 2 + kc) * 512
                      + (q_t * 16 + l15) * 8 + par * 4;
          *(ushort4*)&kp[addr] = o;
        }
      } else {
        unsigned short* dst = (s == 0) ? qo : vo;
        float sc = (s == 0) ? QSCALE : 1.0f;
        int dh0 = e0 & 63;
#pragma unroll
        for (int nb = 0; nb < 4; ++nb) {
          int token = n0 + wn + nb * 16 + l15;
          int bb = token >> 11, ll = token & 2047;
          ushort4 o;
          o.x = f2bf(acc[mb][nb][0] * sc);
          o.y = f2bf(acc[mb][nb][1] * sc);
          o.z = f2bf(acc[mb][nb][2] * sc);
          o.w = f2bf(acc[mb][nb][3] * sc);
          *(ushort4*)&dst[(((size_t)bb * NH + hh) * NL + ll) * DH + dh0] = o;
        }
      }
    } else {
      float4 bv = *(const float4*)&bias[e0];
#pragma unroll
      for (int nb = 0; nb < 4; ++nb) {
        int token = n0 + wn + nb * 16 + l15;
        float4 o;
        o.x = acc[mb][nb][0] + bv.x;
        o.y = acc[mb][nb][1] + bv.y;
        o.z = acc[mb][nb][2] + bv.z;
        o.w = acc[mb][nb][3] + bv.w;
        *(float4*)&out[(size_t)token * ND + e0] = o;
      }
    }
  }
}

// ---------------------------------------------------------------------------
// V fragment repack: v row-major [b,h,l,dh] -> V' frag-major blocks:
// ((bh*64 + jc)*4 + dht)*512 + lane*8 shorts, lane=(q,l15) holds
// V[jc*32 + q*8 + t][dht*16 + l15], t=0..7.  grid (NL/64, NB*NH).
// ---------------------------------------------------------------------------
__global__ __launch_bounds__(256) void repack_v(const unsigned short* __restrict__ v,
                                                unsigned short* __restrict__ vp) {
  __shared__ unsigned short T[64][74];
  const int l0 = blockIdx.x * 64;
  const int bh = blockIdx.y;
  const unsigned short* src = v + ((size_t)bh * NL + l0) * DH;
  unsigned short* dst = vp + (size_t)bh * 131072 + (size_t)(l0 >> 5) * 2048;
#pragma unroll
  for (int p = 0; p < 2; ++p) {
    int c = p * 256 + threadIdx.x;
    int row = c >> 3, seg = c & 7;
    *(uint4*)&T[row][seg * 8] = *(const uint4*)(src + row * DH + seg * 8);
  }
  __syncthreads();
#pragma unroll
  for (int p = 0; p < 2; ++p) {
    int c = p * 256 + threadIdx.x;
    int l15 = c & 15, q = (c >> 4) & 3, dht = (c >> 6) & 3, jcl = c >> 8;
    unsigned short u[8];
#pragma unroll
    for (int t = 0; t < 8; ++t) u[t] = T[jcl * 32 + q * 8 + t][dht * 16 + l15];
    *(uint4*)(dst + (size_t)jcl * 2048 + dht * 512 + (q * 16 + l15) * 8) = *(uint4*)u;
  }
}

// ---------------------------------------------------------------------------
// Flash attention R8: BARRIER-FREE. K'/V' fragments loaded straight from
// global in frag-major layout (one coalesced dwordx4 per fragment). LDS holds
// only the wave-private P round-trip (19.4 KB). Fixed-shift softmax,
// split-j=JS partials (bf16 accO + f32 rsum).
// Block = 256 thr (4 waves); 128 q-rows/block (32/wave, 2 m-blocks).
// q pre-scaled by 0.125*log2e => S already in log2 domain.
// ---------------------------------------------------------------------------
__global__ __launch_bounds__(256, 2) void flash_kernel(
    const unsigned short* __restrict__ qb, const unsigned short* __restrict__ kp,
    const unsigned short* __restrict__ vp, const float* __restrict__ pospad,
    const float* __restrict__ log_sigma, const float* __restrict__ gbias_p,
    const int* __restrict__ ns_p, unsigned short* __restrict__ Pb, float* __restrict__ rsbuf)
{
  const int it = blockIdx.x >> 2;       // 0..15
  const int js = blockIdx.x & 3;        // 0..3
  const int h  = blockIdx.y;
  const int b  = blockIdx.z;
  const int i0 = it * 128;
  const int jbase = js * (NL / JS);     // 512 j per block
  const int Ls = ns_p[0];
  const float gb  = gbias_p[0];
  const float sig = __expf(log_sigma[h]);
  const float CI  = LOG2E * 0.5f / (sig * sig);
  const float A2  = 2.0f * CI;
  const float LGB = LOG2E * gb;
  const float CBL = -8.0f * LOG2E + LGB;   // fixed shift + global-bias base

  const int tid  = threadIdx.x;
  const int wid  = tid >> 6;      // 0..3
  const int lane = tid & 63;
  const int quad = lane >> 4;
  const int l15  = lane & 15;

  __shared__ __align__(16) unsigned short Ps[128][76];   // wave-private rows

  const size_t bh = (size_t)b * NH + h;
  const unsigned short* qbase = qb + (bh * NL + i0) * DH;
  const unsigned short* kpb   = kp + bh * 131072;
  const unsigned short* vpb   = vp + bh * 131072;
  const float* posb = pospad + (size_t)b * NL * 2;

  // hoisted Q A-frags: rows wid*32 + mb*16 + l15
  bf16x8 af[2][2];
#pragma unroll
  for (int mb = 0; mb < 2; ++mb)
#pragma unroll
    for (int kc = 0; kc < 2; ++kc)
      af[mb][kc] = *(const bf16x8*)(qbase + (size_t)(wid * 32 + mb * 16 + l15) * DH + kc * 32 + quad * 8);

  // i-side per-row constants (rows wid*32 + mb*16 + quad*4 + r)
  float pix_[2][4], piy_[2][4], riCm[2][4], ispf[2][4];
#pragma unroll
  for (int mb = 0; mb < 2; ++mb)
#pragma unroll
    for (int r = 0; r < 4; ++r) {
      int ig = i0 + wid * 32 + mb * 16 + quad * 4 + r;
      float2 p2 = *(const float2*)(posb + (size_t)ig * 2);   // zero-padded
      pix_[mb][r] = p2.x; piy_[mb][r] = p2.y;
      ispf[mb][r] = (ig < Ls) ? 1.f : 0.f;
      riCm[mb][r] = -(CI * (p2.x * p2.x + p2.y * p2.y)) - LGB;   // ri - LGB
    }

  f32x4 accO[2][4];   // [mb][dht]
  float rsum[2][4];
#pragma unroll
  for (int mb = 0; mb < 2; ++mb) {
#pragma unroll
    for (int d = 0; d < 4; ++d)
#pragma unroll
      for (int z = 0; z < 4; ++z) accO[mb][d][z] = 0.f;
#pragma unroll
    for (int r = 0; r < 4; ++r) rsum[mb][r] = 0.f;
  }

  for (int jt = 0; jt < NL / JS / 64; ++jt) {
    const int j0 = jbase + jt * 64;

    // ---- K' B-frags: one coalesced 16B/lane load each ----
    bf16x8 kf[4][2];
#pragma unroll
    for (int nb = 0; nb < 4; ++nb)
#pragma unroll
      for (int kc = 0; kc < 2; ++kc)
        kf[nb][kc] = *(const bf16x8*)(kpb + ((size_t)((j0 >> 4) + nb) * 2 + kc) * 512 + lane * 8);

    // ---- j-side constants (j = j0 + nb*16 + l15) ----
    float pjx2[4], pjy2[4], rjC[4], jspf[4];
#pragma unroll
    for (int nb = 0; nb < 4; ++nb) {
      int jg = j0 + nb * 16 + l15;
      float2 p2 = *(const float2*)(posb + (size_t)jg * 2);
      pjx2[nb] = A2 * p2.x; pjy2[nb] = A2 * p2.y;
      rjC[nb]  = -(CI * (p2.x * p2.x + p2.y * p2.y));
      jspf[nb] = (jg < Ls) ? 1.f : 0.f;
    }

    // ---- S = Q' K^T ----
    f32x4 accS[2][4];
#pragma unroll
    for (int mb = 0; mb < 2; ++mb)
#pragma unroll
      for (int nb = 0; nb < 4; ++nb) {
#pragma unroll
        for (int z = 0; z < 4; ++z) accS[mb][nb][z] = 0.f;
        accS[mb][nb] = __builtin_amdgcn_mfma_f32_16x16x32_bf16(af[mb][0], kf[nb][0], accS[mb][nb], 0, 0, 0);
        accS[mb][nb] = __builtin_amdgcn_mfma_f32_16x16x32_bf16(af[mb][1], kf[nb][1], accS[mb][nb], 0, 0, 0);
      }

    // ---- V' B-frags: issue now so they land during the softmax ----
    bf16x8 vf[4][2];
#pragma unroll
    for (int dht = 0; dht < 4; ++dht)
#pragma unroll
      for (int jc = 0; jc < 2; ++jc)
        vf[dht][jc] = *(const bf16x8*)(vpb + ((size_t)((j0 >> 5) + jc) * 4 + dht) * 512 + lane * 8);

    // ---- bias + exp2 + P store (scalar u16, wave-private LDS rows) ----
#pragma unroll
    for (int mb = 0; mb < 2; ++mb)
#pragma unroll
      for (int nb = 0; nb < 4; ++nb)
#pragma unroll
        for (int r = 0; r < 4; ++r) {
          float u = riCm[mb][r] + rjC[nb];
          u = __builtin_fmaf(piy_[mb][r], pjy2[nb], u);
          u = __builtin_fmaf(pix_[mb][r], pjx2[nb], u);
          float msp = ispf[mb][r] * jspf[nb];
          float t = __builtin_fmaf(msp, u, accS[mb][nb][r] + CBL);
          float p = fexp2(t);
          rsum[mb][r] += p;
          Ps[wid * 32 + mb * 16 + quad * 4 + r][nb * 16 + l15] = f2bf(p);
        }

    // ---- P A-frags (b128, same-wave ordering via lgkmcnt) + PV ----
    bf16x8 pf[2][2];
#pragma unroll
    for (int mb = 0; mb < 2; ++mb)
#pragma unroll
      for (int jc = 0; jc < 2; ++jc)
        pf[mb][jc] = *(const bf16x8*)&Ps[wid * 32 + mb * 16 + l15][jc * 32 + quad * 8];
#pragma unroll
    for (int mb = 0; mb < 2; ++mb)
#pragma unroll
      for (int dht = 0; dht < 4; ++dht) {
        accO[mb][dht] = __builtin_amdgcn_mfma_f32_16x16x32_bf16(pf[mb][0], vf[dht][0], accO[mb][dht], 0, 0, 0);
        accO[mb][dht] = __builtin_amdgcn_mfma_f32_16x16x32_bf16(pf[mb][1], vf[dht][1], accO[mb][dht], 0, 0, 0);
      }
  }

  // ---- epilogue: store UNNORMALIZED partials (bf16 accO, f32 rsum) ----
#pragma unroll
  for (int mb = 0; mb < 2; ++mb)
#pragma unroll
    for (int r = 0; r < 4; ++r) {
      float v = rsum[mb][r];
      v += __shfl_xor(v, 1);
      v += __shfl_xor(v, 2);
      v += __shfl_xor(v, 4);
      v += __shfl_xor(v, 8);
      rsum[mb][r] = v;
    }
  const size_t rgbase = (bh * NIT + it) * 128;
  const size_t poff = (size_t)js * RG_TOT * DH;
#pragma unroll
  for (int mb = 0; mb < 2; ++mb)
#pragma unroll
    for (int r = 0; r < 4; ++r) {
      int row = wid * 32 + mb * 16 + quad * 4 + r;
#pragma unroll
      for (int dht = 0; dht < 4; ++dht)
        Pb[poff + (rgbase + row) * DH + dht * 16 + l15] = f2bf(accO[mb][dht][r]);
      if (l15 == 0)
        rsbuf[(size_t)js * RG_TOT + rgbase + row] = rsum[mb][r];
    }
}

// ---------------------------------------------------------------------------
// Combine split-j partials (JS, bf16) -> bf16 attn [b, l, h*64+dh]
// ---------------------------------------------------------------------------
__global__ __launch_bounds__(256) void combine_kernel(const unsigned short* __restrict__ Pb,
                                                      const float* __restrict__ rsbuf,
                                                      unsigned short* __restrict__ attnb) {
  int idx = blockIdx.x * 256 + threadIdx.x;       // over RG_TOT*16 ushort4 chunks
  int rg = idx >> 4, c4 = idx & 15;
  float s0 = 0.f, s1 = 0.f, s2 = 0.f, s3 = 0.f, rsum = 0.f;
#pragma unroll
  for (int js = 0; js < JS; ++js) {
    ushort4 u = *(const ushort4*)&Pb[((size_t)js * RG_TOT + rg) * DH + c4 * 4];
    s0 += bf2f(u.x); s1 += bf2f(u.y); s2 += bf2f(u.z); s3 += bf2f(u.w);
    rsum += rsbuf[(size_t)js * RG_TOT + rg];
  }
  float rs = 1.0f / rsum;
  int bhm = rg >> 11;           // b*8+h
  int l   = rg & 2047;
  int bb  = bhm >> 3, hh = bhm & 7;
  ushort4 o;
  o.x = f2bf(s0 * rs);
  o.y = f2bf(s1 * rs);
  o.z = f2bf(s2 * rs);
  o.w = f2bf(s3 * rs);
  *(ushort4*)&attnb[(((size_t)bb * NL + l) * ND) + hh * DH + c4 * 4] = o;
}

// ---------------------------------------------------------------------------
extern "C" void kernel_launch(void* const* d_in, const int* in_sizes, int n_in,
                              void* d_out, int out_size, void* d_ws, size_t ws_size,
                              hipStream_t stream) {
  const float* x         = (const float*)d_in[0];
  const float* positions = (const float*)d_in[1];
  const float* w_qkv     = (const float*)d_in[2];
  const float* w_out     = (const float*)d_in[3];
  const float* b_out     = (const float*)d_in[4];
  const float* log_sigma = (const float*)d_in[5];
  const float* gbias     = (const float*)d_in[6];
  const int*   ns        = (const int*)d_in[7];

  // workspace layout (shorts unless noted); lifetime overlap:
  //   region R: [wqb] (dead after gemm1)  overlapped by  [Pb | rsbuf] (flash)
  unsigned short* ws  = (unsigned short*)d_ws;
  unsigned short* xb  = ws;                    // 2,097,152 (reused as attn bf16)
  unsigned short* wob = xb  + 2097152;         //   262,144
  unsigned short* qbf = wob + 262144;          // 2,097,152
  unsigned short* kpf = qbf + 2097152;         // 2,097,152 (K' frag-major)
  unsigned short* vbf = kpf + 2097152;         // 2,097,152 (v row-major)
  unsigned short* vpf = vbf + 2097152;         // 2,097,152 (V' frag-major)
  float* pospad = (float*)(vpf + 2097152);     // NB*2048*2 f32
  unsigned short* R   = (unsigned short*)(pospad + NB * NL * 2);
  unsigned short* wqb = R;                     //   786,432 shorts
  unsigned short* Pb  = R;                     // JS*32768*64 bf16 = 16.8 MB
  float* rsbuf = (float*)(Pb + (size_t)JS * RG_TOT * DH);  // JS*32768 f32

  // 1) f32 -> bf16 + zero-padded positions
  cvt_f32_bf16<<<(TOTC + NB * 1024 + 255) / 256, 256, 0, stream>>>(
      x, w_qkv, w_out, positions, ns, xb, wqb, wob, pospad);

  // 2) QKV projection -> q(scaled) row-major, K' frag-major, v row-major
  dim3 g1((3 * NH * DH) / 128, NB * NL / 128);
  gemm_bf16<0, 128><<<g1, 256, 0, stream>>>(wqb, xb, nullptr, qbf, kpf, vbf, nullptr, ND);

  // 3) V' fragment repack
  dim3 gr(NL / 64, NB * NH);
  repack_v<<<gr, 256, 0, stream>>>(vbf, vpf);

  // 4) flash attention partials (split-j=4, barrier-free, frag-direct)
  dim3 g2((NL / 128) * JS, NH, NB);
  flash_kernel<<<g2, 256, 0, stream>>>(qbf, kpf, vpf, pospad, log_sigma, gbias, ns,
                                       Pb, rsbuf);

  // 5) combine -> bf16 attn (into xb)
  combine_kernel<<<RG_TOT * 16 / 256, 256, 0, stream>>>(Pb, rsbuf, xb);

  // 6) output projection (64-row M-tiles: 256 blocks) + bias -> f32 d_out
  dim3 g3(ND / 64, NB * NL / 128);
  gemm_bf16<1, 64><<<g3, 256, 0, stream>>>(wob, xb, b_out, nullptr, nullptr, nullptr,
                                           (float*)d_out, NH * DH);
}